// Round 7
// baseline (580.076 us; speedup 1.0000x reference)
//
#include <hip/hip_runtime.h>

#define NN 512
#define BATCH 256
#define T 8

typedef unsigned long long u64;
typedef unsigned u32;

// u64 max via f64 max: all keys are positive f64 bit patterns (< 2^62,
// exponent never all-ones) -> IEEE order == unsigned order. 1 instr/compare.
__device__ __forceinline__ u64 fm(u64 a, u64 b) {
    return (u64)__double_as_longlong(fmax(__longlong_as_double((long long)a),
                                          __longlong_as_double((long long)b)));
}

#define DPP_FMAX64(k, ctrl) do {                                              \
    int _lo = (int)(u32)(k); int _hi = (int)((k) >> 32);                      \
    int _olo = __builtin_amdgcn_update_dpp(_lo, _lo, ctrl, 0xf, 0xf, false);  \
    int _ohi = __builtin_amdgcn_update_dpp(_hi, _hi, ctrl, 0xf, 0xf, false);  \
    u64 _o = ((u64)(u32)_ohi << 32) | (u32)_olo;                              \
    (k) = fm((k), _o);                                                        \
} while (0)

#define WAVE_FMAX64(k) do {                                                   \
    DPP_FMAX64(k, 0x111); DPP_FMAX64(k, 0x112); DPP_FMAX64(k, 0x114);         \
    DPP_FMAX64(k, 0x118); DPP_FMAX64(k, 0x142); DPP_FMAX64(k, 0x143);         \
} while (0)

__device__ __forceinline__ u64 readlane64(u64 k, int l) {
    u32 lo = (u32)__builtin_amdgcn_readlane((int)(u32)k, l);
    u32 hi = (u32)__builtin_amdgcn_readlane((int)(k >> 32), l);
    return ((u64)hi << 32) | lo;
}

// 3-level select of the alive word for column-word w
__device__ __forceinline__ u64 amsel(int w, u64 a0, u64 a1, u64 a2, u64 a3,
                                     u64 a4, u64 a5, u64 a6, u64 a7) {
    u64 x01 = (w & 1) ? a1 : a0;
    u64 x23 = (w & 1) ? a3 : a2;
    u64 x45 = (w & 1) ? a5 : a4;
    u64 x67 = (w & 1) ? a7 : a6;
    u64 y0 = (w & 2) ? x23 : x01;
    u64 y1 = (w & 2) ? x67 : x45;
    return (w & 4) ? y1 : y0;
}

// ---------------------------------------------------------------------------
// Kernel 1: per-row top-T (desc value, asc col) -> first NN*T u64 of each
// batch's out region (staged to LDS by kernel 2 before outputs land there).
// Entry format: val_bits<<32 | col.   (unchanged, proven)
// ---------------------------------------------------------------------------
__global__ __launch_bounds__(256) void build_top(const float* __restrict__ s,
                                                 float* __restrict__ out) {
    const int wave = threadIdx.x >> 6;
    const int lane = threadIdx.x & 63;
    const int row_g = blockIdx.x * 4 + wave;
    const int b = row_g >> 9;
    const int r = row_g & (NN - 1);
    const float* rp = s + (size_t)row_g * NN;
    u64* dst = (u64*)(out + (size_t)b * NN * NN) + (size_t)r * T;

    const float4 a  = *(const float4*)(rp + 4 * lane);
    const float4 c2 = *(const float4*)(rp + 256 + 4 * lane);

    u64 kk0 = (((u64)__float_as_uint(a.x)  + 1) << 9) | (u32)(511 - (4*lane + 0));
    u64 kk1 = (((u64)__float_as_uint(a.y)  + 1) << 9) | (u32)(511 - (4*lane + 1));
    u64 kk2 = (((u64)__float_as_uint(a.z)  + 1) << 9) | (u32)(511 - (4*lane + 2));
    u64 kk3 = (((u64)__float_as_uint(a.w)  + 1) << 9) | (u32)(511 - (4*lane + 3));
    u64 kk4 = (((u64)__float_as_uint(c2.x) + 1) << 9) | (u32)(511 - (256 + 4*lane + 0));
    u64 kk5 = (((u64)__float_as_uint(c2.y) + 1) << 9) | (u32)(511 - (256 + 4*lane + 1));
    u64 kk6 = (((u64)__float_as_uint(c2.z) + 1) << 9) | (u32)(511 - (256 + 4*lane + 2));
    u64 kk7 = (((u64)__float_as_uint(c2.w) + 1) << 9) | (u32)(511 - (256 + 4*lane + 3));

    #pragma unroll
    for (int t = 0; t < T; ++t) {
        u64 m0 = fm(kk0, kk1), m1 = fm(kk2, kk3);
        u64 m2 = fm(kk4, kk5), m3 = fm(kk6, kk7);
        m0 = fm(m0, m1); m2 = fm(m2, m3);
        u64 bk = fm(m0, m2);
        WAVE_FMAX64(bk);
        bk = readlane64(bk, 63);

        const int wcol = 511 - (int)(bk & 511);
        const u32 vb = (u32)(bk >> 9) - 1u;
        if (lane == 0) dst[t] = ((u64)vb << 32) | (u32)wcol;

        const int owner = (wcol & 255) >> 2;
        const int slot  = ((wcol >> 8) << 2) | (wcol & 3);
        if (lane == owner) {
            kk0 = (slot == 0) ? 0 : kk0;  kk1 = (slot == 1) ? 0 : kk1;
            kk2 = (slot == 2) ? 0 : kk2;  kk3 = (slot == 3) ? 0 : kk3;
            kk4 = (slot == 4) ? 0 : kk4;  kk5 = (slot == 5) ? 0 : kk5;
            kk6 = (slot == 6) ? 0 : kk6;  kk7 = (slot == 7) ? 0 : kk7;
        }
    }
}

// ---------------------------------------------------------------------------
// Kernel 2: eager-light greedy matching, one wave per batch element.
// key = (val_bits+1)<<32 | (512-row)<<16 | col ; DEAD sentinel = 512
// (never matches any cstar in [0,511], and sorts below all live keys).
// Heads are ALWAYS valid at pop time: after each accept, rows whose head
// column died are re-headed immediately via the cooperative 8-lane list
// probe (or rare HBM reload). Exactly NN iterations, no validity branch.
// ---------------------------------------------------------------------------
#define DEADK 512ull

__global__ __launch_bounds__(64) void greedy_match(const float* __restrict__ s,
                                                   float* __restrict__ out) {
    __shared__ __align__(16) u64 lst[NN][T];   // 32 KB

    const int b = blockIdx.x;
    const int lane = threadIdx.x;
    const float* sb = s + (size_t)b * NN * NN;
    float* ob = out + (size_t)b * NN * NN;

    // ---- stage candidate lists from out-region into LDS ----
    {
        const ulonglong2* src = (const ulonglong2*)ob;
        ulonglong2* dstl = (ulonglong2*)&lst[0][0];
        #pragma unroll
        for (int j = 0; j < 32; ++j)
            dstl[lane + 64 * j] = src[lane + 64 * j];
    }

    u64 am0 = ~0ull, am1 = ~0ull, am2 = ~0ull, am3 = ~0ull,
        am4 = ~0ull, am5 = ~0ull, am6 = ~0ull, am7 = ~0ull;

    u64 k0, k1, k2, k3, k4, k5, k6, k7;
#define INITK(j, KJ) do {                                                     \
        const int r_ = lane + 64 * (j);                                       \
        const u64 e_ = lst[r_][0];                                            \
        KJ = (((e_ >> 32) + 1ull) << 32)                                      \
           | ((u64)(u32)(512 - r_) << 16) | (e_ & 511ull);                    \
    } while (0)
    INITK(0, k0); INITK(1, k1); INITK(2, k2); INITK(3, k3);
    INITK(4, k4); INITK(5, k5); INITK(6, k6); INITK(7, k7);
#undef INITK

    #pragma unroll 1
    for (int step = 0; step < NN; ++step) {
        // ---- pop: argmax over all 512 keys (heads always valid) ----
        u64 m0 = fm(k0, k1), m1 = fm(k2, k3), m2 = fm(k4, k5), m3 = fm(k6, k7);
        m0 = fm(m0, m1); m2 = fm(m2, m3);
        u64 bk = fm(m0, m2);
        WAVE_FMAX64(bk);
        const u32 lo = (u32)__builtin_amdgcn_readlane((int)(u32)bk, 63);
        const int cstar = (int)(lo & 511u);
        const int rstar = 512 - (int)((lo >> 16) & 1023u);
        const u32 cu = (u32)cstar;

        // ---- write output row rstar (fire-and-forget) ----
        float4 o0, o1;
        o0.x = (4 * lane + 0 == cstar) ? 1.0f : 0.0f;
        o0.y = (4 * lane + 1 == cstar) ? 1.0f : 0.0f;
        o0.z = (4 * lane + 2 == cstar) ? 1.0f : 0.0f;
        o0.w = (4 * lane + 3 == cstar) ? 1.0f : 0.0f;
        o1.x = (256 + 4 * lane + 0 == cstar) ? 1.0f : 0.0f;
        o1.y = (256 + 4 * lane + 1 == cstar) ? 1.0f : 0.0f;
        o1.z = (256 + 4 * lane + 2 == cstar) ? 1.0f : 0.0f;
        o1.w = (256 + 4 * lane + 3 == cstar) ? 1.0f : 0.0f;
        float* orow = ob + ((size_t)rstar << 9);
        *(float4*)(orow + 4 * lane) = o0;
        *(float4*)(orow + 256 + 4 * lane) = o1;

        // ---- kill col cstar (wave-uniform replicated masks) ----
        {
            const int cw = cstar >> 6;
            const u64 nb = ~(1ull << (cstar & 63));
            am0 = (cw == 0) ? (am0 & nb) : am0;  am1 = (cw == 1) ? (am1 & nb) : am1;
            am2 = (cw == 2) ? (am2 & nb) : am2;  am3 = (cw == 3) ? (am3 & nb) : am3;
            am4 = (cw == 4) ? (am4 & nb) : am4;  am5 = (cw == 5) ? (am5 & nb) : am5;
            am6 = (cw == 6) ? (am6 & nb) : am6;  am7 = (cw == 7) ? (am7 & nb) : am7;
        }

        // ---- kill row rstar (dead sentinel) ----
        {
            const int rl = rstar & 63, rj = rstar >> 6;
            const bool mine = (lane == rl);
            k0 = (mine && rj == 0) ? DEADK : k0;  k1 = (mine && rj == 1) ? DEADK : k1;
            k2 = (mine && rj == 2) ? DEADK : k2;  k3 = (mine && rj == 3) ? DEADK : k3;
            k4 = (mine && rj == 4) ? DEADK : k4;  k5 = (mine && rj == 5) ? DEADK : k5;
            k6 = (mine && rj == 6) ? DEADK : k6;  k7 = (mine && rj == 7) ? DEADK : k7;
        }

        // ---- eager fix: re-head rows whose head col just died ----
        // dead sentinel (512) never matches cu in [0,511] -> 1 cmp per key
        u32 m8 = 0;
        m8 |= ((((u32)k0) & 1023u) == cu) ? 1u   : 0u;
        m8 |= ((((u32)k1) & 1023u) == cu) ? 2u   : 0u;
        m8 |= ((((u32)k2) & 1023u) == cu) ? 4u   : 0u;
        m8 |= ((((u32)k3) & 1023u) == cu) ? 8u   : 0u;
        m8 |= ((((u32)k4) & 1023u) == cu) ? 16u  : 0u;
        m8 |= ((((u32)k5) & 1023u) == cu) ? 32u  : 0u;
        m8 |= ((((u32)k6) & 1023u) == cu) ? 64u  : 0u;
        m8 |= ((((u32)k7) & 1023u) == cu) ? 128u : 0u;

        u64 mk = __ballot(m8 != 0u);
        while (mk) {
            const int l = (int)__builtin_ctzll(mk);
            u32 lm = (u32)__builtin_amdgcn_readlane((int)m8, l);
            mk &= mk - 1;
            while (lm) {
                const int j = (int)__builtin_ctz(lm);
                lm &= lm - 1;
                const int row = l + 64 * j;
                const u64 rowf = (u64)(u32)(512 - row) << 16;

                // cooperative probe: lanes 0..7 hold the row's 8 list entries
                const u64 e = lst[row][lane & 7];
                const int c = (int)(e & 511u);
                const u64 w = amsel(c >> 6, am0, am1, am2, am3, am4, am5, am6, am7);
                const bool al = ((w >> (c & 63)) & 1ull) != 0ull;
                const u64 mask = __ballot(al) & 0xFFull;

                u64 nk;
                if (mask) {
                    const int idx = (int)__builtin_ctzll(mask);
                    const u64 es = readlane64(e, idx);
                    nk = (((es >> 32) + 1ull) << 32) | rowf | (es & 511ull);
                } else {
                    // cold: cooperative HBM reload, top-1 among alive cols
                    const float* rp = sb + (size_t)row * NN;
                    const float4 fa = *(const float4*)(rp + 4 * lane);
                    const float4 fv = *(const float4*)(rp + 256 + 4 * lane);
                    const int sh = (4 * lane) & 63; const int wq = lane >> 4;
                    u64 xlo = (wq == 0) ? am0 : (wq == 1) ? am1 : (wq == 2) ? am2 : am3;
                    u64 xhi = (wq == 0) ? am4 : (wq == 1) ? am5 : (wq == 2) ? am6 : am7;
                    const u32 al8 = ((u32)(xlo >> sh) & 0xFu)
                                  | (((u32)(xhi >> sh) & 0xFu) << 4);
                    u64 c0 = (al8 & 1u)   ? ((((u64)__float_as_uint(fa.x) + 1) << 9) | (u32)(511 - (4*lane+0))) : 0;
                    u64 c1 = (al8 & 2u)   ? ((((u64)__float_as_uint(fa.y) + 1) << 9) | (u32)(511 - (4*lane+1))) : 0;
                    u64 c2 = (al8 & 4u)   ? ((((u64)__float_as_uint(fa.z) + 1) << 9) | (u32)(511 - (4*lane+2))) : 0;
                    u64 c3 = (al8 & 8u)   ? ((((u64)__float_as_uint(fa.w) + 1) << 9) | (u32)(511 - (4*lane+3))) : 0;
                    u64 c4 = (al8 & 16u)  ? ((((u64)__float_as_uint(fv.x) + 1) << 9) | (u32)(511 - (256+4*lane+0))) : 0;
                    u64 c5 = (al8 & 32u)  ? ((((u64)__float_as_uint(fv.y) + 1) << 9) | (u32)(511 - (256+4*lane+1))) : 0;
                    u64 c6 = (al8 & 64u)  ? ((((u64)__float_as_uint(fv.z) + 1) << 9) | (u32)(511 - (256+4*lane+2))) : 0;
                    u64 c7 = (al8 & 128u) ? ((((u64)__float_as_uint(fv.w) + 1) << 9) | (u32)(511 - (256+4*lane+3))) : 0;
                    u64 n0 = fm(c0, c1), n1 = fm(c2, c3);
                    u64 n2 = fm(c4, c5), n3 = fm(c6, c7);
                    n0 = fm(n0, n1); n2 = fm(n2, n3);
                    u64 bw = fm(n0, n2);
                    WAVE_FMAX64(bw);
                    bw = readlane64(bw, 63);
                    const int wc = 511 - (int)(bw & 511);
                    nk = ((bw >> 9) << 32) | rowf | (u32)wc;
                }

                // write nk into (lane l, slot j)
                const bool mine = (lane == l);
                k0 = (mine && j == 0) ? nk : k0;  k1 = (mine && j == 1) ? nk : k1;
                k2 = (mine && j == 2) ? nk : k2;  k3 = (mine && j == 3) ? nk : k3;
                k4 = (mine && j == 4) ? nk : k4;  k5 = (mine && j == 5) ? nk : k5;
                k6 = (mine && j == 6) ? nk : k6;  k7 = (mine && j == 7) ? nk : k7;
            }
        }
    }
}

extern "C" void kernel_launch(void* const* d_in, const int* in_sizes, int n_in,
                              void* d_out, int out_size, void* d_ws, size_t ws_size,
                              hipStream_t stream) {
    const float* s = (const float*)d_in[0];
    float* out = (float*)d_out;

    build_top<<<dim3(BATCH * NN / 4), dim3(256), 0, stream>>>(s, out);
    greedy_match<<<dim3(BATCH), dim3(64), 0, stream>>>(s, out);
}